// Round 11
// baseline (2917.952 us; speedup 1.0000x reference)
//
#include <hip/hip_runtime.h>
#include <math.h>

// corr: (B=8, HW=4096, H=64, W=64) fp32; out same shape.
// out[b,s,p] = corr[b,s,p] * g[sy-iy(p)] * g[sx-ix(p)], idx(p)=argmax_s corr[b,s,p].
//
// Persistent pipelined kernel, NO per-pixel atomics (R9 lesson), all-linear
// streams (R10 lesson), L3 slab reuse (R9-proven: FETCH=0.56GB).
// 512 blocks x 512 thr = 2 blocks/CU co-resident. Per 2-batch group g:
//   A(g): block = 16-row panel, linear 256KB read, split-K argmax partials
//         (packed u64) -> pp[g&1] via plain disjoint stores.
//   R(g): 128 blocks reduce 256 partials/pixel -> fidx[g&1] (shfl-combined).
//   B(g): same panel geometry; NT loads (hit L3 slab), separable Gaussian
//         from 127-entry LDS table, NT stores.
// Schedule: A0 | R0|A1 | R1|B0 | B1|A2 | R2|A3 | R3|B2 | B3   (6 barriers)
constexpr int HWc  = 4096;
constexpr int ROWS = 16;                 // rows per panel (256KB contiguous)
constexpr int PAN  = HWc / ROWS;         // 256 panels per batch
constexpr int NBLK = 512;
constexpr int NTHR = 512;

typedef float f32x4 __attribute__((ext_vector_type(4)));
typedef unsigned long long u64;

__device__ __forceinline__ unsigned monokey(float f) {
    unsigned u = __float_as_uint(f);
    return u ^ ((unsigned)(((int)u) >> 31) | 0x80000000u);
}
__device__ __forceinline__ u64 packkey(float m, int idx) {
    // larger value wins; ties -> larger (4095-idx) == smaller idx == first
    // occurrence (matches jnp.argmax). Max is order-independent.
    return ((u64)monokey(m) << 32) | (unsigned)(4095 - idx);
}

// Grid barrier (R9-verified): monotone counter, zeroed per call by memset.
__device__ __forceinline__ void gridbar(unsigned* cnt, unsigned target) {
    __threadfence();
    __syncthreads();
    if (threadIdx.x == 0) {
        __hip_atomic_fetch_add(cnt, 1u, __ATOMIC_ACQ_REL, __HIP_MEMORY_SCOPE_AGENT);
        while (__hip_atomic_load(cnt, __ATOMIC_ACQUIRE, __HIP_MEMORY_SCOPE_AGENT) < target)
            __builtin_amdgcn_s_sleep(32);
    }
    __syncthreads();
    __threadfence();
}

// A: argmax partial over one 16-row panel of batch b -> pp[buf].
__device__ __forceinline__ void a_job(const float* __restrict__ corr,
                                      u64* __restrict__ pp,
                                      int buf, int bl, int b, int rr) {
    int s0 = rr * ROWS;
    int px = threadIdx.x * 8;
    const float* src = corr + (size_t)b * HWc * HWc + (size_t)s0 * HWc + px;

    float bm[8]; int bi[8];
    #pragma unroll
    for (int e = 0; e < 8; ++e) { bm[e] = -INFINITY; bi[e] = 0; }

    #pragma unroll 4
    for (int r = 0; r < ROWS; ++r) {
        f32x4 va = *reinterpret_cast<const f32x4*>(src + (size_t)r * HWc);
        f32x4 vb = *reinterpret_cast<const f32x4*>(src + (size_t)r * HWc + 4);
        int k = s0 + r;
        #pragma unroll
        for (int e = 0; e < 4; ++e) {
            if (va[e] > bm[e])     { bm[e]     = va[e]; bi[e]     = k; }
            if (vb[e] > bm[e + 4]) { bm[e + 4] = vb[e]; bi[e + 4] = k; }
        }
    }
    u64* dst = pp + ((((size_t)buf * 2 + bl) * PAN + rr) << 12) + px;
    #pragma unroll
    for (int e = 0; e < 8; ++e) dst[e] = packkey(bm[e], bi[e]);
}

// R: blocks 0..127 reduce PAN partials -> fidx[buf]. 8 threads per pixel
// (32 partials each), combined with 3 shfl_xor steps.
__device__ __forceinline__ void r_job(const u64* __restrict__ pp,
                                      u64* __restrict__ fidx, int buf) {
    int t    = blockIdx.x * NTHR + threadIdx.x;   // < 65536
    int sub  = t & 7;
    int task = t >> 3;                            // 0..8191
    int bl   = task >> 12;
    int px   = task & 4095;

    const u64* src = pp + (((size_t)buf * 2 + bl) * PAN << 12) + px;
    u64 best = 0;
    int j0 = sub * 32;
    #pragma unroll 8
    for (int j = j0; j < j0 + 32; ++j) {
        u64 v = __builtin_nontemporal_load(src + ((size_t)j << 12));
        best = v > best ? v : best;
    }
    #pragma unroll
    for (int m = 1; m <= 4; m <<= 1) {
        u64 o = __shfl_xor(best, m, 64);
        best = o > best ? o : best;
    }
    if (sub == 0) fidx[(((size_t)buf * 2 + bl) << 12) + px] = best;
}

// B: apply over one 16-row panel. sy const per panel; gx(r)=gtab[ic+r].
__device__ __forceinline__ void b_job(const float* __restrict__ corr,
                                      const u64* __restrict__ fidx,
                                      float* __restrict__ out,
                                      const float* __restrict__ gtab,
                                      int buf, int bl, int b, int rr) {
    int s0 = rr * ROWS, sy = s0 >> 6, sxb = s0 & 63;
    int px = threadIdx.x * 8;
    const u64* f = fidx + (((size_t)buf * 2 + bl) << 12) + px;

    float gy[8]; int ic[8];
    #pragma unroll
    for (int e = 0; e < 8; ++e) {
        int idx = 4095 - (int)(unsigned)(f[e] & 0xFFFFFFFFull);
        gy[e] = gtab[sy - (idx >> 6) + 63];
        ic[e] = sxb + 63 - (idx & 63);
    }

    size_t base = (size_t)b * HWc * HWc + (size_t)s0 * HWc + px;
    const float* cs = corr + base;
    float*       os = out  + base;

    #pragma unroll 4
    for (int r = 0; r < ROWS; ++r) {
        f32x4 va = __builtin_nontemporal_load(reinterpret_cast<const f32x4*>(cs + (size_t)r * HWc));
        f32x4 vb = __builtin_nontemporal_load(reinterpret_cast<const f32x4*>(cs + (size_t)r * HWc + 4));
        f32x4 oa, ob;
        #pragma unroll
        for (int e = 0; e < 4; ++e) {
            oa[e] = va[e] * gy[e]     * gtab[ic[e] + r];
            ob[e] = vb[e] * gy[e + 4] * gtab[ic[e + 4] + r];
        }
        __builtin_nontemporal_store(oa, reinterpret_cast<f32x4*>(os + (size_t)r * HWc));
        __builtin_nontemporal_store(ob, reinterpret_cast<f32x4*>(os + (size_t)r * HWc + 4));
    }
}

__global__ __launch_bounds__(NTHR, 4) void k_persist(
        const float* __restrict__ corr, float* __restrict__ out,
        u64* __restrict__ pp, u64* __restrict__ fidx,
        unsigned* __restrict__ cnt) {
    __shared__ float gtab[128];                   // g[d+63], d in [-63,63]
    if (threadIdx.x < 128) {
        float d = (float)((int)threadIdx.x - 63);
        gtab[threadIdx.x] = __expf(-d * d * (1.0f / 50.0f));   // 2*sigma^2 = 50
    }
    __syncthreads();

    int bid = blockIdx.x;
    int bl  = bid & 1;                            // batch within group
    int rr  = bid >> 1;                           // panel index [0,256)
    bool rb = bid < 128;                          // reduce-duty blocks

    // P0: A0
    a_job(corr, pp, 0, bl, 0 + bl, rr);
    gridbar(cnt, 1 * NBLK);
    // P1: R0 || A1
    if (rb) r_job(pp, fidx, 0);
    a_job(corr, pp, 1, bl, 2 + bl, rr);
    gridbar(cnt, 2 * NBLK);
    // P2: R1 || B0
    if (rb) r_job(pp, fidx, 1);
    b_job(corr, fidx, out, gtab, 0, bl, 0 + bl, rr);
    gridbar(cnt, 3 * NBLK);
    // P3: B1 || A2  (alternate order by parity to interleave read/write)
    if (bl) {
        a_job(corr, pp, 0, bl, 4 + bl, rr);
        b_job(corr, fidx, out, gtab, 1, bl, 2 + bl, rr);
    } else {
        b_job(corr, fidx, out, gtab, 1, bl, 2 + bl, rr);
        a_job(corr, pp, 0, bl, 4 + bl, rr);
    }
    gridbar(cnt, 4 * NBLK);
    // P4: R2 || A3
    if (rb) r_job(pp, fidx, 0);
    a_job(corr, pp, 1, bl, 6 + bl, rr);
    gridbar(cnt, 5 * NBLK);
    // P5: R3 || B2
    if (rb) r_job(pp, fidx, 1);
    b_job(corr, fidx, out, gtab, 0, bl, 4 + bl, rr);
    gridbar(cnt, 6 * NBLK);
    // P6: B3
    b_job(corr, fidx, out, gtab, 1, bl, 6 + bl, rr);
}

extern "C" void kernel_launch(void* const* d_in, const int* in_sizes, int n_in,
                              void* d_out, int out_size, void* d_ws, size_t ws_size,
                              hipStream_t stream) {
    const float* corr = (const float*)d_in[0];
    float* out = (float*)d_out;

    // ws: pp 2bufs x 2batch x 256panel x 4096px u64 = 32MB; fidx 2x2x4096 u64
    // = 128KB; counter. pp/fidx fully overwritten before every read ->
    // poison-safe; counter zeroed per call -> deterministic across replays.
    u64* pp   = (u64*)d_ws;
    u64* fidx = pp + (size_t)2 * 2 * PAN * HWc;
    unsigned* cnt = (unsigned*)(fidx + (size_t)2 * 2 * HWc);
    hipMemsetAsync(cnt, 0, 256, stream);

    k_persist<<<NBLK, NTHR, 0, stream>>>(corr, out, pp, fidx, cnt);
}

// Round 13
// 859.899 us; speedup vs baseline: 3.3934x; 3.3934x over previous
//
#include <hip/hip_runtime.h>
#include <math.h>

// corr: (B=8, HW=4096, H=64, W=64) fp32; out same shape.
// out[b,s,p] = corr[b,s,p] * g[sy-iy(p)] * g[sx-ix(p)], idx(p)=argmax_s corr[b,s,p].
//
// Persistent pipelined kernel. R11 structure unchanged; ONLY the grid barrier
// is fixed: spin uses RELAXED agent loads (no per-iteration buffer_inv /
// L2-invalidate storm -- the R9/R11 killer), one ACQUIRE fence on exit.
constexpr int HWc  = 4096;
constexpr int ROWS = 16;                 // rows per panel (256KB contiguous)
constexpr int PAN  = HWc / ROWS;         // 256 panels per batch
constexpr int NBLK = 512;
constexpr int NTHR = 512;

typedef float f32x4 __attribute__((ext_vector_type(4)));
typedef unsigned long long u64;

__device__ __forceinline__ unsigned monokey(float f) {
    unsigned u = __float_as_uint(f);
    return u ^ ((unsigned)(((int)u) >> 31) | 0x80000000u);
}
__device__ __forceinline__ u64 packkey(float m, int idx) {
    // larger value wins; ties -> larger (4095-idx) == smaller idx == first
    // occurrence (matches jnp.argmax). Max is order-independent.
    return ((u64)monokey(m) << 32) | (unsigned)(4095 - idx);
}

// Grid barrier, storm-free:
//   arrive: RELEASE fetch_add (flushes this XCD's dirty lines for cross-XCD
//           readers).
//   spin:   RELAXED loads -- plain global load, NO cache invalidate.
//   exit:   single ACQUIRE agent fence (one buffer_inv) so post-barrier reads
//           don't see stale L2 lines.
__device__ __forceinline__ void gridbar(unsigned* cnt, unsigned target) {
    __syncthreads();
    if (threadIdx.x == 0) {
        __hip_atomic_fetch_add(cnt, 1u, __ATOMIC_RELEASE, __HIP_MEMORY_SCOPE_AGENT);
        while (__hip_atomic_load(cnt, __ATOMIC_RELAXED, __HIP_MEMORY_SCOPE_AGENT) < target)
            __builtin_amdgcn_s_sleep(8);
    }
    __syncthreads();
    __builtin_amdgcn_fence(__ATOMIC_ACQUIRE, "agent");
}

// A: argmax partial over one 16-row panel of batch b -> pp[buf].
__device__ __forceinline__ void a_job(const float* __restrict__ corr,
                                      u64* __restrict__ pp,
                                      int buf, int bl, int b, int rr) {
    int s0 = rr * ROWS;
    int px = threadIdx.x * 8;
    const float* src = corr + (size_t)b * HWc * HWc + (size_t)s0 * HWc + px;

    float bm[8]; int bi[8];
    #pragma unroll
    for (int e = 0; e < 8; ++e) { bm[e] = -INFINITY; bi[e] = 0; }

    #pragma unroll 4
    for (int r = 0; r < ROWS; ++r) {
        f32x4 va = *reinterpret_cast<const f32x4*>(src + (size_t)r * HWc);
        f32x4 vb = *reinterpret_cast<const f32x4*>(src + (size_t)r * HWc + 4);
        int k = s0 + r;
        #pragma unroll
        for (int e = 0; e < 4; ++e) {
            if (va[e] > bm[e])     { bm[e]     = va[e]; bi[e]     = k; }
            if (vb[e] > bm[e + 4]) { bm[e + 4] = vb[e]; bi[e + 4] = k; }
        }
    }
    u64* dst = pp + ((((size_t)buf * 2 + bl) * PAN + rr) << 12) + px;
    #pragma unroll
    for (int e = 0; e < 8; ++e) dst[e] = packkey(bm[e], bi[e]);
}

// R: blocks 0..127 reduce PAN partials -> fidx[buf]. 8 threads per pixel
// (32 partials each), combined with 3 shfl_xor steps.
__device__ __forceinline__ void r_job(const u64* __restrict__ pp,
                                      u64* __restrict__ fidx, int buf) {
    int t    = blockIdx.x * NTHR + threadIdx.x;   // < 65536
    int sub  = t & 7;
    int task = t >> 3;                            // 0..8191
    int bl   = task >> 12;
    int px   = task & 4095;

    const u64* src = pp + (((size_t)buf * 2 + bl) * PAN << 12) + px;
    u64 best = 0;
    int j0 = sub * 32;
    #pragma unroll 8
    for (int j = j0; j < j0 + 32; ++j) {
        u64 v = __builtin_nontemporal_load(src + ((size_t)j << 12));
        best = v > best ? v : best;
    }
    #pragma unroll
    for (int m = 1; m <= 4; m <<= 1) {
        u64 o = __shfl_xor(best, m, 64);
        best = o > best ? o : best;
    }
    if (sub == 0) fidx[(((size_t)buf * 2 + bl) << 12) + px] = best;
}

// B: apply over one 16-row panel. sy const per panel; gx(r)=gtab[ic+r].
__device__ __forceinline__ void b_job(const float* __restrict__ corr,
                                      const u64* __restrict__ fidx,
                                      float* __restrict__ out,
                                      const float* __restrict__ gtab,
                                      int buf, int bl, int b, int rr) {
    int s0 = rr * ROWS, sy = s0 >> 6, sxb = s0 & 63;
    int px = threadIdx.x * 8;
    const u64* f = fidx + (((size_t)buf * 2 + bl) << 12) + px;

    float gy[8]; int ic[8];
    #pragma unroll
    for (int e = 0; e < 8; ++e) {
        int idx = 4095 - (int)(unsigned)(f[e] & 0xFFFFFFFFull);
        gy[e] = gtab[sy - (idx >> 6) + 63];
        ic[e] = sxb + 63 - (idx & 63);
    }

    size_t base = (size_t)b * HWc * HWc + (size_t)s0 * HWc + px;
    const float* cs = corr + base;
    float*       os = out  + base;

    #pragma unroll 4
    for (int r = 0; r < ROWS; ++r) {
        f32x4 va = __builtin_nontemporal_load(reinterpret_cast<const f32x4*>(cs + (size_t)r * HWc));
        f32x4 vb = __builtin_nontemporal_load(reinterpret_cast<const f32x4*>(cs + (size_t)r * HWc + 4));
        f32x4 oa, ob;
        #pragma unroll
        for (int e = 0; e < 4; ++e) {
            oa[e] = va[e] * gy[e]     * gtab[ic[e] + r];
            ob[e] = vb[e] * gy[e + 4] * gtab[ic[e + 4] + r];
        }
        __builtin_nontemporal_store(oa, reinterpret_cast<f32x4*>(os + (size_t)r * HWc));
        __builtin_nontemporal_store(ob, reinterpret_cast<f32x4*>(os + (size_t)r * HWc + 4));
    }
}

__global__ __launch_bounds__(NTHR, 4) void k_persist(
        const float* __restrict__ corr, float* __restrict__ out,
        u64* __restrict__ pp, u64* __restrict__ fidx,
        unsigned* __restrict__ cnt) {
    __shared__ float gtab[128];                   // g[d+63], d in [-63,63]
    if (threadIdx.x < 128) {
        float d = (float)((int)threadIdx.x - 63);
        gtab[threadIdx.x] = __expf(-d * d * (1.0f / 50.0f));   // 2*sigma^2 = 50
    }
    __syncthreads();

    int bid = blockIdx.x;
    int bl  = bid & 1;                            // batch within group
    int rr  = bid >> 1;                           // panel index [0,256)
    bool rb = bid < 128;                          // reduce-duty blocks

    // Schedule: A0 | R0|A1 | R1|B0 | B1|A2 | R2|A3 | R3|B2 | B3
    a_job(corr, pp, 0, bl, 0 + bl, rr);
    gridbar(cnt, 1 * NBLK);
    if (rb) r_job(pp, fidx, 0);
    a_job(corr, pp, 1, bl, 2 + bl, rr);
    gridbar(cnt, 2 * NBLK);
    if (rb) r_job(pp, fidx, 1);
    b_job(corr, fidx, out, gtab, 0, bl, 0 + bl, rr);
    gridbar(cnt, 3 * NBLK);
    if (bl) {
        a_job(corr, pp, 0, bl, 4 + bl, rr);
        b_job(corr, fidx, out, gtab, 1, bl, 2 + bl, rr);
    } else {
        b_job(corr, fidx, out, gtab, 1, bl, 2 + bl, rr);
        a_job(corr, pp, 0, bl, 4 + bl, rr);
    }
    gridbar(cnt, 4 * NBLK);
    if (rb) r_job(pp, fidx, 0);
    a_job(corr, pp, 1, bl, 6 + bl, rr);
    gridbar(cnt, 5 * NBLK);
    if (rb) r_job(pp, fidx, 1);
    b_job(corr, fidx, out, gtab, 0, bl, 4 + bl, rr);
    gridbar(cnt, 6 * NBLK);
    b_job(corr, fidx, out, gtab, 1, bl, 6 + bl, rr);
}

extern "C" void kernel_launch(void* const* d_in, const int* in_sizes, int n_in,
                              void* d_out, int out_size, void* d_ws, size_t ws_size,
                              hipStream_t stream) {
    const float* corr = (const float*)d_in[0];
    float* out = (float*)d_out;

    // ws: pp 2bufs x 2batch x 256panel x 4096px u64 = 32MB; fidx 2x2x4096 u64
    // = 128KB; counter. pp/fidx fully overwritten before every read ->
    // poison-safe; counter zeroed per call -> deterministic across replays.
    u64* pp   = (u64*)d_ws;
    u64* fidx = pp + (size_t)2 * 2 * PAN * HWc;
    unsigned* cnt = (unsigned*)(fidx + (size_t)2 * 2 * HWc);
    (void)hipMemsetAsync(cnt, 0, 256, stream);

    k_persist<<<NBLK, NTHR, 0, stream>>>(corr, out, pp, fidx, cnt);
}

// Round 14
// 439.534 us; speedup vs baseline: 6.6387x; 1.9564x over previous
//
#include <hip/hip_runtime.h>
#include <math.h>

// corr: (B=8, HW=4096, H=64, W=64) fp32; out same shape.
// out[b,s,p] = corr[b,s,p] * g[sy-iy(p)] * g[sx-ix(p)], idx(p)=argmax_s corr[b,s,p].
//
// Stream-ordered software pipeline, NO device-side sync (R9-R13 lesson:
// grid barriers are toxic here; kernel boundaries give free release/acquire).
// Launch L runs three independent roles in one grid (role = blockIdx split):
//   A(L):   argmax partials of batch L     (linear HBM reads -> pp[L&1])
//   R(L-1): reduce partials -> fidx        (L2/L3 reads, tiny)
//   B(L-2): apply pass of batch L-2        (L3 reads of slab staged by A two
//           launches ago -- R9-proven; separable Gaussian; NT stores)
// A-reads and B-writes overlap within every launch => HBM stays busy both
// directions the whole run. GRP=1: <=3 slabs (192MB) live in L3 at once.
constexpr int HWc  = 4096;
constexpr int ROWS = 16;                 // rows per A/B panel (256KB contiguous)
constexpr int PAN  = HWc / ROWS;         // 256 panels per batch
constexpr int NTHR = 512;
constexpr int NA   = 2 * PAN;            // 512: even bids A, odd bids B
constexpr int NRB  = 64;                 // reduce blocks
constexpr int NBLK = NA + NRB;           // 576 blocks per launch

typedef float f32x4 __attribute__((ext_vector_type(4)));
typedef unsigned long long u64;

__device__ __forceinline__ unsigned monokey(float f) {
    unsigned u = __float_as_uint(f);
    return u ^ ((unsigned)(((int)u) >> 31) | 0x80000000u);
}
__device__ __forceinline__ u64 packkey(float m, int idx) {
    // larger value wins; ties -> larger (4095-idx) == smaller idx == first
    // occurrence (matches jnp.argmax). Normal data, no NaN.
    return ((u64)monokey(m) << 32) | (unsigned)(4095 - idx);
}

__global__ __launch_bounds__(NTHR) void k_step(
        const float* __restrict__ corr, float* __restrict__ out,
        u64* __restrict__ pp, u64* __restrict__ fidx,
        int bA, int bR, int bB) {
    int bid = blockIdx.x;

    if (bid >= NA) {                       // ---- R role: reduce bR's partials
        if (bR < 0) return;
        int t   = (bid - NA) * NTHR + threadIdx.x;   // 32768 threads
        int sub = t & 7;
        int px  = t >> 3;                            // 0..4095
        const u64* src = pp + (((size_t)(bR & 1) * PAN) << 12) + px;
        u64 best = 0;
        int j0 = sub * (PAN / 8);
        #pragma unroll 8
        for (int j = j0; j < j0 + PAN / 8; ++j) {
            u64 v = src[(size_t)j << 12];
            best = v > best ? v : best;
        }
        #pragma unroll
        for (int m = 1; m <= 4; m <<= 1) {
            u64 o = __shfl_xor(best, m, 64);
            best = o > best ? o : best;
        }
        if (sub == 0) fidx[(((size_t)(bR & 1)) << 12) + px] = best;
        return;
    }

    int rr = bid >> 1;                     // panel index 0..255

    if ((bid & 1) == 0) {                  // ---- A role: argmax partials of bA
        if (bA < 0) return;
        int s0 = rr * ROWS;
        int px = threadIdx.x * 8;
        const float* src = corr + (size_t)bA * HWc * HWc + (size_t)s0 * HWc + px;

        float bm[8]; int bi[8];
        #pragma unroll
        for (int e = 0; e < 8; ++e) { bm[e] = -INFINITY; bi[e] = 0; }

        #pragma unroll 4
        for (int r = 0; r < ROWS; ++r) {
            f32x4 va = *reinterpret_cast<const f32x4*>(src + (size_t)r * HWc);
            f32x4 vb = *reinterpret_cast<const f32x4*>(src + (size_t)r * HWc + 4);
            int k = s0 + r;
            #pragma unroll
            for (int e = 0; e < 4; ++e) {
                if (va[e] > bm[e])     { bm[e]     = va[e]; bi[e]     = k; }
                if (vb[e] > bm[e + 4]) { bm[e + 4] = vb[e]; bi[e + 4] = k; }
            }
        }
        u64* dst = pp + ((((size_t)(bA & 1) * PAN + rr)) << 12) + px;
        #pragma unroll
        for (int e = 0; e < 8; ++e) dst[e] = packkey(bm[e], bi[e]);
        return;
    }

    // ---- B role: apply pass of batch bB, panel rr
    if (bB < 0) return;

    __shared__ float gtab[128];            // g[d+63], d in [-63,63]
    if (threadIdx.x < 128) {
        float d = (float)((int)threadIdx.x - 63);
        gtab[threadIdx.x] = __expf(-d * d * (1.0f / 50.0f));   // 2*sigma^2 = 50
    }
    __syncthreads();

    int s0 = rr * ROWS, sy = s0 >> 6, sxb = s0 & 63;
    int px = threadIdx.x * 8;
    const u64* f = fidx + (((size_t)(bB & 1)) << 12) + px;

    float gy[8]; int ic[8];
    #pragma unroll
    for (int e = 0; e < 8; ++e) {
        int idx = 4095 - (int)(unsigned)(f[e] & 0xFFFFFFFFull);
        gy[e] = gtab[sy - (idx >> 6) + 63];
        ic[e] = sxb + 63 - (idx & 63);     // gx(r) = gtab[ic + r]
    }

    size_t base = (size_t)bB * HWc * HWc + (size_t)s0 * HWc + px;
    const float* cs = corr + base;
    float*       os = out  + base;

    #pragma unroll 4
    for (int r = 0; r < ROWS; ++r) {
        f32x4 va = __builtin_nontemporal_load(reinterpret_cast<const f32x4*>(cs + (size_t)r * HWc));
        f32x4 vb = __builtin_nontemporal_load(reinterpret_cast<const f32x4*>(cs + (size_t)r * HWc + 4));
        f32x4 oa, ob;
        #pragma unroll
        for (int e = 0; e < 4; ++e) {
            oa[e] = va[e] * gy[e]     * gtab[ic[e] + r];
            ob[e] = vb[e] * gy[e + 4] * gtab[ic[e + 4] + r];
        }
        __builtin_nontemporal_store(oa, reinterpret_cast<f32x4*>(os + (size_t)r * HWc));
        __builtin_nontemporal_store(ob, reinterpret_cast<f32x4*>(os + (size_t)r * HWc + 4));
    }
}

extern "C" void kernel_launch(void* const* d_in, const int* in_sizes, int n_in,
                              void* d_out, int out_size, void* d_ws, size_t ws_size,
                              hipStream_t stream) {
    const float* corr = (const float*)d_in[0];
    float* out = (float*)d_out;

    // ws: pp 2 bufs x 256 panels x 4096 px u64 = 16 MB; fidx 2 x 4096 u64.
    // Both fully overwritten before each read (stream order) -> poison-safe,
    // deterministic across graph replays. No memset needed.
    u64* pp   = (u64*)d_ws;
    u64* fidx = pp + (size_t)2 * PAN * HWc;

    // Pipeline over 8 batches: L: A(L) || R(L-1) || B(L-2)
    for (int L = 0; L < 10; ++L) {
        int bA = (L <= 7) ? L : -1;
        int bR = (L >= 1 && L <= 8) ? L - 1 : -1;
        int bB = (L >= 2) ? L - 2 : -1;
        k_step<<<NBLK, NTHR, 0, stream>>>(corr, out, pp, fidx, bA, bR, bB);
    }
}